// Round 1
// baseline (104.662 us; speedup 1.0000x reference)
//
#include <hip/hip_runtime.h>
#include <hip/hip_bf16.h>
#include <stdint.h>

// MX fp8_e4m3 fake-quantize, group=32 along last dim.
// out = dequant(quant(x / scale)) * scale, scale = pow2(floor(log2(absmax))-8),
// clipped to [-127,127]-ish and floored at 1e-5.

__device__ __forceinline__ float mx_quant_elem(float xx, float inv, float scale) {
    float v  = xx * inv;              // x / scale (exact: scale is a power of two)
    float av = fabsf(v);
    // priv_exp = max(floor(log2(|v|)), -6); bit-exact via exponent field.
    int e = (int)(__float_as_uint(av) >> 23) - 127;   // denorm/zero -> -127
    e = (e < -6) ? -6 : e;
    // sc = 2^(3 - e)  (MBITS-2 = 3)
    float sc    = __uint_as_float((uint32_t)(130 - e) << 23);
    float scinv = __uint_as_float((uint32_t)(124 + e) << 23);  // 2^(e-3)
    // nearest, half away from zero: sign * floor(|v*sc| + 0.5)
    float r = floorf(fmaf(av, sc, 0.5f));   // av*sc exact (pow2), fma safe
    r = r * scinv;
    r = fminf(r, 448.0f);                   // saturate e4m3 max-normal
    float q = copysignf(r, v);
    return q * scale;
}

__global__ void __launch_bounds__(256) mxq_kernel(const float* __restrict__ x,
                                                  float* __restrict__ out,
                                                  int nvec4) {
    const float4* __restrict__ x4 = reinterpret_cast<const float4*>(x);
    float4* __restrict__ o4       = reinterpret_cast<float4*>(out);
    int idx    = blockIdx.x * blockDim.x + threadIdx.x;
    int stride = gridDim.x * blockDim.x;
    for (int i = idx; i < nvec4; i += stride) {
        float4 v = x4[i];
        // per-lane absmax of 4 elems
        float a = fmaxf(fmaxf(fabsf(v.x), fabsf(v.y)),
                        fmaxf(fabsf(v.z), fabsf(v.w)));
        // reduce absmax across the 8 lanes covering one 32-elem group
        a = fmaxf(a, __shfl_xor(a, 1));
        a = fmaxf(a, __shfl_xor(a, 2));
        a = fmaxf(a, __shfl_xor(a, 4));
        // shared scale: se = floor(log2(max)) - 8, clipped; scale = max(2^se, 1e-5)
        int me = (int)(__float_as_uint(a) >> 23);  // biased exponent (a >= 0)
        int se = me - 135;                         // me==0 (zero/denorm) -> -135
        // 2^-17 < 1e-5 < 2^-16, and se<-127 clamp also lands at 1e-5
        float scale = (se < -16) ? 1e-5f
                                 : __uint_as_float((uint32_t)(se + 127) << 23);
        float inv = 1.0f / scale;                  // exact for pow2 scale
        float4 r;
        r.x = mx_quant_elem(v.x, inv, scale);
        r.y = mx_quant_elem(v.y, inv, scale);
        r.z = mx_quant_elem(v.z, inv, scale);
        r.w = mx_quant_elem(v.w, inv, scale);
        o4[i] = r;
    }
}

extern "C" void kernel_launch(void* const* d_in, const int* in_sizes, int n_in,
                              void* d_out, int out_size, void* d_ws, size_t ws_size,
                              hipStream_t stream) {
    const float* x = (const float*)d_in[0];
    float* out     = (float*)d_out;
    int n     = in_sizes[0];
    int nvec4 = n >> 2;                 // 8192*8192 / 4
    int threads = 256;
    int blocks  = 2048;                 // grid-stride; ~8 blocks/CU
    mxq_kernel<<<blocks, threads, 0, stream>>>(x, out, nvec4);
}